// Round 5
// baseline (117.181 us; speedup 1.0000x reference)
//
#include <hip/hip_runtime.h>

#define SROWS 16384
#define DIMK  4096
#define NE    64
#define BM    64
#define NBLK  (SROWS/BM)        // 256 blocks = 1/CU
#define KSEG  2048              // k-range per k-split half
#define NCHK  (KSEG/32)         // 64 K32 chunks per half
#define WSPLIT_SHORTS 262144    // 512 kslots * 64 experts * 8 = shorts per (hi|lo) plane
#define WSOFF_F 262144          // float offset of block-partials region (skip 1 MB W-split)
#define NW    8

typedef __attribute__((ext_vector_type(8))) short short8;
typedef __attribute__((ext_vector_type(4))) float f32x4;

__device__ __forceinline__ unsigned short bf16_rne(float f) {
    unsigned u = __float_as_uint(f);
    return (unsigned short)((u + 0x7fffu + ((u >> 16) & 1u)) >> 16);
}

// split 8 f32 -> 8 hi bf16 + 8 lo bf16 (exact: f ≈ hi + lo to ~2^-17 rel)
__device__ __forceinline__ void split8(const float4 a, const float4 c, short8& hi, short8& lo) {
    float f[8] = {a.x, a.y, a.z, a.w, c.x, c.y, c.z, c.w};
    #pragma unroll
    for (int i = 0; i < 8; ++i) {
        unsigned short h = bf16_rne(f[i]);
        float hf = __uint_as_float((unsigned)h << 16);
        unsigned short l = bf16_rne(f[i] - hf);
        hi[i] = (short)h;
        lo[i] = (short)l;
    }
}

// pre-pass: split W into bf16 hi/lo planes in B-fragment order [hilo][k/8][e][8]
__global__ void w_split(const float* __restrict__ W, unsigned short* __restrict__ wsp)
{
    const int idx   = blockIdx.x * 256 + threadIdx.x;   // 0..32767
    const int kslot = idx & 511;
    const int e     = idx >> 9;
    const float* p = W + (size_t)e * DIMK + kslot * 8;
    float4 va = *reinterpret_cast<const float4*>(p);
    float4 vb = *reinterpret_cast<const float4*>(p + 4);
    short8 hi, lo;
    split8(va, vb, hi, lo);
    *reinterpret_cast<short8*>(wsp + (size_t)(kslot * 64 + e) * 8)                 = hi;
    *reinterpret_cast<short8*>(wsp + WSPLIT_SHORTS + (size_t)(kslot * 64 + e) * 8) = lo;
}

__global__ __launch_bounds__(512, 2) void gate_main(
    const float* __restrict__ x, const unsigned short* __restrict__ wsp,
    const float* __restrict__ b, float* __restrict__ out, float* __restrict__ ws)
{
    __shared__ float smem[9280];          // epilogue only: part[4096] | Lb[4160] | red[1024]
    float* const part = smem;
    float* const Lb   = smem + 4096;
    float* const red  = smem + 8256;

    const int tid  = threadIdx.x;
    const int lane = tid & 63;
    const int wid  = __builtin_amdgcn_readfirstlane(tid >> 6);  // 0..7
    const int ksw  = wid >> 2;            // k-split half
    const int mw   = wid & 3;             // 16-row M-tile
    const int row0 = blockIdx.x * BM;

    // A: this lane's fragment address (row = lane&15 in tile, k-slice = (lane>>4)*8)
    const float* xA = x + (size_t)(row0 + mw * 16 + (lane & 15)) * DIMK
                        + ksw * KSEG + (lane >> 4) * 8;
    // B: fragment base in pre-split W (hi plane; lo at +WSPLIT_SHORTS)
    const unsigned short* wB = wsp
        + ((size_t)(ksw * (KSEG / 8) + (lane >> 4)) * 64 + (lane & 15)) * 8;

    f32x4 acc[4];
    #pragma unroll
    for (int n = 0; n < 4; ++n) acc[n] = (f32x4){0.f, 0.f, 0.f, 0.f};

    // ---- 2-stage software pipeline, no LDS, no barriers ----
    float4 a0x = *reinterpret_cast<const float4*>(xA);
    float4 a0y = *reinterpret_cast<const float4*>(xA + 4);
    short8 b0h[4], b0l[4], b1h[4], b1l[4];
    #pragma unroll
    for (int n = 0; n < 4; ++n) {
        b0h[n] = *reinterpret_cast<const short8*>(wB + n * 128);
        b0l[n] = *reinterpret_cast<const short8*>(wB + WSPLIT_SHORTS + n * 128);
    }
    float4 a1x = *reinterpret_cast<const float4*>(xA + 32);
    float4 a1y = *reinterpret_cast<const float4*>(xA + 36);
    #pragma unroll
    for (int n = 0; n < 4; ++n) {
        b1h[n] = *reinterpret_cast<const short8*>(wB + 2048 + n * 128);
        b1l[n] = *reinterpret_cast<const short8*>(wB + WSPLIT_SHORTS + 2048 + n * 128);
    }

    #pragma unroll 1
    for (int ch = 0; ch < NCHK; ch += 2) {
        short8 ah, al;
        // ---- stage 0: chunk ch ----
        split8(a0x, a0y, ah, al);
        if (ch + 2 < NCHK) {
            a0x = *reinterpret_cast<const float4*>(xA + (ch + 2) * 32);
            a0y = *reinterpret_cast<const float4*>(xA + (ch + 2) * 32 + 4);
        }
        #pragma unroll
        for (int n = 0; n < 4; ++n)
            acc[n] = __builtin_amdgcn_mfma_f32_16x16x32_bf16(ah, b0h[n], acc[n], 0, 0, 0);
        #pragma unroll
        for (int n = 0; n < 4; ++n)
            acc[n] = __builtin_amdgcn_mfma_f32_16x16x32_bf16(al, b0h[n], acc[n], 0, 0, 0);
        #pragma unroll
        for (int n = 0; n < 4; ++n)
            acc[n] = __builtin_amdgcn_mfma_f32_16x16x32_bf16(ah, b0l[n], acc[n], 0, 0, 0);
        #pragma unroll
        for (int n = 0; n < 4; ++n)
            acc[n] = __builtin_amdgcn_mfma_f32_16x16x32_bf16(al, b0l[n], acc[n], 0, 0, 0);
        if (ch + 2 < NCHK) {
            #pragma unroll
            for (int n = 0; n < 4; ++n) {
                b0h[n] = *reinterpret_cast<const short8*>(wB + (ch + 2) * 2048 + n * 128);
                b0l[n] = *reinterpret_cast<const short8*>(wB + WSPLIT_SHORTS + (ch + 2) * 2048 + n * 128);
            }
        }
        // ---- stage 1: chunk ch+1 ----
        split8(a1x, a1y, ah, al);
        if (ch + 3 < NCHK) {
            a1x = *reinterpret_cast<const float4*>(xA + (ch + 3) * 32);
            a1y = *reinterpret_cast<const float4*>(xA + (ch + 3) * 32 + 4);
        }
        #pragma unroll
        for (int n = 0; n < 4; ++n)
            acc[n] = __builtin_amdgcn_mfma_f32_16x16x32_bf16(ah, b1h[n], acc[n], 0, 0, 0);
        #pragma unroll
        for (int n = 0; n < 4; ++n)
            acc[n] = __builtin_amdgcn_mfma_f32_16x16x32_bf16(al, b1h[n], acc[n], 0, 0, 0);
        #pragma unroll
        for (int n = 0; n < 4; ++n)
            acc[n] = __builtin_amdgcn_mfma_f32_16x16x32_bf16(ah, b1l[n], acc[n], 0, 0, 0);
        #pragma unroll
        for (int n = 0; n < 4; ++n)
            acc[n] = __builtin_amdgcn_mfma_f32_16x16x32_bf16(al, b1l[n], acc[n], 0, 0, 0);
        if (ch + 3 < NCHK) {
            #pragma unroll
            for (int n = 0; n < 4; ++n) {
                b1h[n] = *reinterpret_cast<const short8*>(wB + (ch + 3) * 2048 + n * 128);
                b1l[n] = *reinterpret_cast<const short8*>(wB + WSPLIT_SHORTS + (ch + 3) * 2048 + n * 128);
            }
        }
    }

    // ---- k-pair reduce (ks=1 waves dump, ks=0 waves sum) ----
    __syncthreads();
    if (wid >= 4) {
        #pragma unroll
        for (int n = 0; n < 4; ++n)
            #pragma unroll
            for (int j = 0; j < 4; ++j)
                part[(wid - 4) * 1024 + lane * 16 + n * 4 + j] = acc[n][j];
    }
    __syncthreads();
    if (wid < 4) {
        #pragma unroll
        for (int n = 0; n < 4; ++n) {
            #pragma unroll
            for (int j = 0; j < 4; ++j) {
                float v = acc[n][j] + part[wid * 1024 + lane * 16 + n * 4 + j];
                // C layout (m89-verified): col = lane&15, row = (lane>>4)*4 + j
                const int e  = n * 16 + (lane & 15);
                const int rl = mw * 16 + (lane >> 4) * 4 + j;
                Lb[e * 65 + rl] = v;
            }
        }
    }
    __syncthreads();

    // ---- epilogue (R2/R4-proven): softmax + top-2 per row, lane = expert ----
    float impAcc = 0.f, cntAcc = 0.f;
    const float blane = b[lane];
    float* outIdx = out;
    float* outVal = out + (size_t)SROWS * 2;

    #pragma unroll 1
    for (int rr = 0; rr < 8; ++rr) {
        const int r = wid * 8 + rr;
        const float logit = Lb[lane * 65 + r] + blane;

        float v1 = logit; int i1 = lane;
        #pragma unroll
        for (int off = 32; off; off >>= 1) {
            float ov = __shfl_xor(v1, off);
            int   oi = __shfl_xor(i1, off);
            if (ov > v1 || (ov == v1 && oi < i1)) { v1 = ov; i1 = oi; }
        }
        float p = expf(logit - v1);
        float ssum = p;
        #pragma unroll
        for (int off = 32; off; off >>= 1) ssum += __shfl_xor(ssum, off);

        float v2 = (lane == i1) ? -3.402823466e38f : logit;
        int i2 = lane;
        #pragma unroll
        for (int off = 32; off; off >>= 1) {
            float ov = __shfl_xor(v2, off);
            int   oi = __shfl_xor(i2, off);
            if (ov > v2 || (ov == v2 && oi < i2)) { v2 = ov; i2 = oi; }
        }

        impAcc += p / ssum;
        cntAcc += (i1 == lane) ? 1.f : 0.f;

        if (lane == 0) {
            const int sr2 = row0 + r;
            outIdx[sr2 * 2 + 0] = (float)i1;
            outIdx[sr2 * 2 + 1] = (float)i2;
            outVal[sr2 * 2 + 0] = 1.f / ssum;
            outVal[sr2 * 2 + 1] = expf(v2 - v1) / ssum;
        }
    }

    // ---- per-block reduce of importance / count partials ----
    __syncthreads();
    red[wid * 64 + lane]           = impAcc;
    red[NW * 64 + wid * 64 + lane] = cntAcc;
    __syncthreads();
    if (tid < 64) {
        float si = 0.f, sc2 = 0.f;
        #pragma unroll
        for (int g = 0; g < NW; ++g) {
            si  += red[g * 64 + tid];
            sc2 += red[NW * 64 + g * 64 + tid];
        }
        ws[WSOFF_F + (size_t)blockIdx.x * 64 + tid] = si;
        ws[WSOFF_F + (size_t)NBLK * 64 + (size_t)blockIdx.x * 64 + tid] = sc2;
    }
}

__global__ void gate_reduce(const float* __restrict__ ws, float* __restrict__ out)
{
    __shared__ float li[4 * 64], lc[4 * 64], lp[64];
    const int t = threadIdx.x;
    const int e = t & 63, g = t >> 6;
    float si = 0.f, sc = 0.f;
    const int per = NBLK / 4;     // 64
    for (int bb = g * per; bb < (g + 1) * per; ++bb) {
        si += ws[WSOFF_F + (size_t)bb * 64 + e];
        sc += ws[WSOFF_F + (size_t)NBLK * 64 + (size_t)bb * 64 + e];
    }
    li[g * 64 + e] = si;
    lc[g * 64 + e] = sc;
    __syncthreads();
    if (t < 64) {
        float ti = 0.f, tc = 0.f;
        #pragma unroll
        for (int gg = 0; gg < 4; ++gg) { ti += li[gg * 64 + t]; tc += lc[gg * 64 + t]; }
        lp[t] = ti * tc;
    }
    __syncthreads();
    if (t == 0) {
        float s = 0.f;
        for (int i = 0; i < NE; ++i) s += lp[i];
        out[(size_t)SROWS * 4] = s * ((float)NE / ((float)SROWS * (float)SROWS));
    }
}

extern "C" void kernel_launch(void* const* d_in, const int* in_sizes, int n_in,
                              void* d_out, int out_size, void* d_ws, size_t ws_size,
                              hipStream_t stream)
{
    const float* x = (const float*)d_in[0];
    const float* W = (const float*)d_in[1];
    const float* b = (const float*)d_in[2];
    float* out = (float*)d_out;
    unsigned short* wsp = (unsigned short*)d_ws;
    float* wsf = (float*)d_ws;

    w_split<<<128, 256, 0, stream>>>(W, wsp);
    gate_main<<<NBLK, 512, 0, stream>>>(x, wsp, b, out, wsf);
    gate_reduce<<<1, 256, 0, stream>>>(wsf, out);
}